// Round 1
// baseline (796.056 us; speedup 1.0000x reference)
//
#include <hip/hip_runtime.h>
#include <hip/hip_bf16.h>

// SAGAN attention block: B=4, C=256, N=64*64=4096.
// Pipeline: prep_w (bf16 hi/lo split of weights), prep_x (transpose x -> Xt[n][c], hi/lo split),
// conv_fg (3-pass split-bf16 MFMA -> fT,gT split), conv_h (single bf16 -> h[c][n]),
// flash attention (QK 3-pass for accurate scores, online softmax, PV single bf16),
// conv_out (f32 output). Requires ws_size >= ~68 MB.

typedef short short8 __attribute__((ext_vector_type(8)));
typedef float f32x4 __attribute__((ext_vector_type(4)));
typedef unsigned short u16;

#define DEV static __device__ __forceinline__
#define MFMA(a, b, c) __builtin_amdgcn_mfma_f32_16x16x32_bf16(a, b, c, 0, 0, 0)

DEV u16 b16(float x) {
    __hip_bfloat16 h = __float2bfloat16(x);
    return *reinterpret_cast<u16*>(&h);
}
DEV float f16f(u16 u) {
    union { unsigned int ui; float f; } c;
    c.ui = ((unsigned int)u) << 16;
    return c.f;
}
DEV short8 ld8(const u16* p) { return *reinterpret_cast<const short8*>(p); }

constexpr int NB = 4;
constexpr int NC = 256;
constexpr int NN = 4096;
constexpr int NM = NB * NN;  // 16384

// workspace byte offsets (all 16B aligned)
constexpr size_t OFF_WFH = 0;
constexpr size_t OFF_WFL = 131072;
constexpr size_t OFF_WGH = 262144;
constexpr size_t OFF_WGL = 393216;
constexpr size_t OFF_WHB = 524288;
constexpr size_t OFF_WVB = 655360;
constexpr size_t OFF_XTH = 786432;
constexpr size_t OFF_XTL = OFF_XTH + 8388608;
constexpr size_t OFF_FH  = OFF_XTL + 8388608;
constexpr size_t OFF_FL  = OFF_FH  + 8388608;
constexpr size_t OFF_GH  = OFF_FL  + 8388608;
constexpr size_t OFF_GL  = OFF_GH  + 8388608;
constexpr size_t OFF_HB  = OFF_GL  + 8388608;
constexpr size_t OFF_OT  = OFF_HB  + 8388608;
// total = OFF_OT + 8388608 = 67,895,296 bytes

// ---------------- weight prep: bf16 + hi/lo splits ----------------
__global__ __launch_bounds__(256) void k_prep_w(
    const float* __restrict__ Wf, const float* __restrict__ Wg,
    const float* __restrict__ Wh, const float* __restrict__ Wv,
    u16* WFH, u16* WFL, u16* WGH, u16* WGL, u16* WHB, u16* WVB) {
    int i = blockIdx.x * 256 + threadIdx.x;  // 65536 threads exactly
    float fv = Wf[i];
    u16 fh = b16(fv);
    WFH[i] = fh;
    WFL[i] = b16(fv - f16f(fh));
    float gv = Wg[i];
    u16 gh = b16(gv);
    WGH[i] = gh;
    WGL[i] = b16(gv - f16f(gh));
    WHB[i] = b16(Wh[i]);
    WVB[i] = b16(Wv[i]);
}

// ---------------- x transpose + split: x[b][c][n] f32 -> Xt[b][n][c] bf16 hi/lo ----------------
__global__ __launch_bounds__(256) void k_prep_x(const float* __restrict__ x, u16* XtH, u16* XtL) {
    __shared__ float lds[64][65];
    int bid = blockIdx.x;                 // 1024 blocks: b(4) x ctile(4) x ntile(64)
    int b = bid >> 8, rem = bid & 255, ct = rem >> 6, nt = rem & 63;
    int tid = threadIdx.x;
    int tx = tid & 63, ty = tid >> 6;
    const float* src = x + ((size_t)(b * 256 + ct * 64)) * 4096 + nt * 64;
#pragma unroll
    for (int k = 0; k < 16; ++k) {
        int cl = ty * 16 + k;
        lds[cl][tx] = src[(size_t)cl * 4096 + tx];
    }
    __syncthreads();
    int nl = tid >> 2, cg = tid & 3;
    short8 h0, h1, l0, l1;
#pragma unroll
    for (int j = 0; j < 8; ++j) {
        float v = lds[cg * 16 + j][nl];
        u16 hb = b16(v);
        h0[j] = (short)hb;
        l0[j] = (short)b16(v - f16f(hb));
    }
#pragma unroll
    for (int j = 8; j < 16; ++j) {
        float v = lds[cg * 16 + j][nl];
        u16 hb = b16(v);
        h1[j - 8] = (short)hb;
        l1[j - 8] = (short)b16(v - f16f(hb));
    }
    size_t dst = ((size_t)(b * 4096 + nt * 64 + nl)) * 256 + ct * 64 + cg * 16;
    *reinterpret_cast<short8*>(XtH + dst) = h0;
    *reinterpret_cast<short8*>(XtH + dst + 8) = h1;
    *reinterpret_cast<short8*>(XtL + dst) = l0;
    *reinterpret_cast<short8*>(XtL + dst + 8) = l1;
}

// ---------------- conv f,g: fT[m][o] = sum_c Xt[m][c]*Wf[o][c] + bf[o], 3-pass split ----------------
__global__ __launch_bounds__(256) void k_conv_fg(
    const u16* __restrict__ XtH, const u16* __restrict__ XtL,
    const u16* __restrict__ WFH, const u16* __restrict__ WFL,
    const u16* __restrict__ WGH, const u16* __restrict__ WGL,
    const float* __restrict__ bf, const float* __restrict__ bg,
    u16* FH, u16* FL, u16* GH, u16* GL) {
    int bidm = blockIdx.x & 255, bido = blockIdx.x >> 8;
    int w = threadIdx.x >> 6, lane = threadIdx.x & 63, r = lane & 15, g = lane >> 4;
    int m0 = bidm * 64 + w * 16, o0 = bido * 64;
    f32x4 fa[4], ga[4];
#pragma unroll
    for (int i = 0; i < 4; ++i) { fa[i] = {0.f, 0.f, 0.f, 0.f}; ga[i] = {0.f, 0.f, 0.f, 0.f}; }
    const u16* arh = XtH + (size_t)(m0 + r) * 256;
    const u16* arl = XtL + (size_t)(m0 + r) * 256;
#pragma unroll
    for (int ks = 0; ks < 8; ++ks) {
        int k0 = ks * 32 + 8 * g;
        short8 ah = ld8(arh + k0);
        short8 al = ld8(arl + k0);
#pragma unroll
        for (int ot = 0; ot < 4; ++ot) {
            size_t wrow = (size_t)(o0 + ot * 16 + r) * 256 + k0;
            short8 wfh = ld8(WFH + wrow), wfl = ld8(WFL + wrow);
            short8 wgh = ld8(WGH + wrow), wgl = ld8(WGL + wrow);
            fa[ot] = MFMA(ah, wfh, fa[ot]);
            fa[ot] = MFMA(ah, wfl, fa[ot]);
            fa[ot] = MFMA(al, wfh, fa[ot]);
            ga[ot] = MFMA(ah, wgh, ga[ot]);
            ga[ot] = MFMA(ah, wgl, ga[ot]);
            ga[ot] = MFMA(al, wgh, ga[ot]);
        }
    }
#pragma unroll
    for (int ot = 0; ot < 4; ++ot) {
#pragma unroll
        for (int q = 0; q < 4; ++q) {
            int row = m0 + 4 * g + q;
            int col = o0 + ot * 16 + r;
            size_t idx = (size_t)row * 256 + col;
            float fv = fa[ot][q] + bf[col];
            float gv = ga[ot][q] + bg[col];
            u16 fhi = b16(fv);
            FH[idx] = fhi;
            FL[idx] = b16(fv - f16f(fhi));
            u16 ghi = b16(gv);
            GH[idx] = ghi;
            GL[idx] = b16(gv - f16f(ghi));
        }
    }
}

// ---------------- conv h: h[b][o][n] = sum_c Wh[o][c]*Xt[b*N+n][c] + bh[o] (bf16 out, [C][N] layout) ----------------
__global__ __launch_bounds__(256) void k_conv_h(
    const u16* __restrict__ WHB, const u16* __restrict__ XtH,
    const float* __restrict__ bh, u16* Hb) {
    int bidn = blockIdx.x & 255, bido = blockIdx.x >> 8;
    int w = threadIdx.x >> 6, lane = threadIdx.x & 63, r = lane & 15, g = lane >> 4;
    int o0 = bido * 64 + w * 16, n0 = bidn * 64;
    f32x4 acc[4];
#pragma unroll
    for (int i = 0; i < 4; ++i) acc[i] = {0.f, 0.f, 0.f, 0.f};
    const u16* arow = WHB + (size_t)(o0 + r) * 256;
#pragma unroll
    for (int ks = 0; ks < 8; ++ks) {
        int k0 = ks * 32 + 8 * g;
        short8 a = ld8(arow + k0);
#pragma unroll
        for (int ntl = 0; ntl < 4; ++ntl) {
            short8 bb = ld8(XtH + (size_t)(n0 + ntl * 16 + r) * 256 + k0);
            acc[ntl] = MFMA(a, bb, acc[ntl]);
        }
    }
#pragma unroll
    for (int ntl = 0; ntl < 4; ++ntl) {
#pragma unroll
        for (int q = 0; q < 4; ++q) {
            int o = o0 + 4 * g + q;
            int nf = n0 + ntl * 16 + r;
            int bb = nf >> 12, n = nf & 4095;
            Hb[((size_t)(bb * 256 + o)) * 4096 + n] = b16(acc[ntl][q] + bh[o]);
        }
    }
}

// ---------------- flash attention: per wave 16 queries, online softmax over 4096 keys ----------------
DEV float rmax16(float v) {
    v = fmaxf(v, __shfl_xor(v, 1));
    v = fmaxf(v, __shfl_xor(v, 2));
    v = fmaxf(v, __shfl_xor(v, 4));
    v = fmaxf(v, __shfl_xor(v, 8));
    return v;
}
DEV float rsum16(float v) {
    v += __shfl_xor(v, 1);
    v += __shfl_xor(v, 2);
    v += __shfl_xor(v, 4);
    v += __shfl_xor(v, 8);
    return v;
}

__global__ __launch_bounds__(64) void k_attn(
    const u16* __restrict__ FH, const u16* __restrict__ FL,
    const u16* __restrict__ GH, const u16* __restrict__ GL,
    const u16* __restrict__ Hb, u16* OT) {
    int b = blockIdx.x >> 8, jt = blockIdx.x & 255;
    int lane = threadIdx.x, r = lane & 15, g = lane >> 4;
    int j0 = jt * 16;
    const float L2E = 1.4426950408889634f;

    // Q resident in registers (hi+lo): A-frag rows j=r
    short8 Qh[8], Ql[8];
    {
        const u16* qh = GH + (size_t)(b * 4096 + j0 + r) * 256;
        const u16* ql = GL + (size_t)(b * 4096 + j0 + r) * 256;
#pragma unroll
        for (int k = 0; k < 8; ++k) {
            Qh[k] = ld8(qh + k * 32 + 8 * g);
            Ql[k] = ld8(ql + k * 32 + 8 * g);
        }
    }
    f32x4 O[16];
#pragma unroll
    for (int i = 0; i < 16; ++i) O[i] = {0.f, 0.f, 0.f, 0.f};
    float m[4], l[4];
#pragma unroll
    for (int q = 0; q < 4; ++q) { m[q] = -1e30f; l[q] = 0.f; }

    __shared__ u16 P[16][72];  // padded to break bank conflicts

    for (int i0 = 0; i0 < 4096; i0 += 64) {
        // S'[j][i] for 4 i-tiles, 3-pass split for accuracy (softmax amplifies abs error)
        f32x4 s[4];
#pragma unroll
        for (int it = 0; it < 4; ++it) s[it] = {0.f, 0.f, 0.f, 0.f};
#pragma unroll
        for (int it = 0; it < 4; ++it) {
            const u16* krh = FH + (size_t)(b * 4096 + i0 + it * 16 + r) * 256;
            const u16* krl = FL + (size_t)(b * 4096 + i0 + it * 16 + r) * 256;
#pragma unroll
            for (int k = 0; k < 8; ++k) {
                short8 kh = ld8(krh + k * 32 + 8 * g);
                short8 kl = ld8(krl + k * 32 + 8 * g);
                s[it] = MFMA(Qh[k], kh, s[it]);
                s[it] = MFMA(Qh[k], kl, s[it]);
                s[it] = MFMA(Ql[k], kh, s[it]);
            }
        }
        // online softmax; row j = 4g+q lives in 16 lanes of group g, cols = r
        float corr[4];
#pragma unroll
        for (int q = 0; q < 4; ++q) {
            float v = fmaxf(fmaxf(s[0][q], s[1][q]), fmaxf(s[2][q], s[3][q]));
            v = rmax16(v);
            float mn = fmaxf(m[q], v);
            corr[q] = exp2f((m[q] - mn) * L2E);
            float rs = 0.f;
#pragma unroll
            for (int it = 0; it < 4; ++it) {
                float p = exp2f((s[it][q] - mn) * L2E);
                s[it][q] = p;
                rs += p;
            }
            rs = rsum16(rs);
            l[q] = l[q] * corr[q] + rs;
            m[q] = mn;
        }
#pragma unroll
        for (int ct = 0; ct < 16; ++ct) {
            O[ct][0] *= corr[0];
            O[ct][1] *= corr[1];
            O[ct][2] *= corr[2];
            O[ct][3] *= corr[3];
        }
        // P -> LDS (D-layout row=4g+q, col=it*16+r), then re-read as A-frags
#pragma unroll
        for (int it = 0; it < 4; ++it) {
#pragma unroll
            for (int q = 0; q < 4; ++q) P[4 * g + q][it * 16 + r] = b16(s[it][q]);
        }
        __syncthreads();  // single wave: forces lgkmcnt drain before frag reads
        short8 pa0 = *reinterpret_cast<const short8*>(&P[r][8 * g]);
        short8 pa1 = *reinterpret_cast<const short8*>(&P[r][32 + 8 * g]);
        // PV: O[j][c] += P[j][i] * V[i][c]; Bt[c][i] = h[c][i] (natural layout)
#pragma unroll
        for (int ct = 0; ct < 16; ++ct) {
            const u16* vrow = Hb + (size_t)(b * 256 + ct * 16 + r) * 4096 + i0 + 8 * g;
            short8 v0 = ld8(vrow);
            short8 v1 = ld8(vrow + 32);
            O[ct] = MFMA(pa0, v0, O[ct]);
            O[ct] = MFMA(pa1, v1, O[ct]);
        }
        __syncthreads();
    }
    float inv[4];
#pragma unroll
    for (int q = 0; q < 4; ++q) inv[q] = 1.f / l[q];
#pragma unroll
    for (int ct = 0; ct < 16; ++ct) {
#pragma unroll
        for (int q = 0; q < 4; ++q) {
            OT[(size_t)(b * 4096 + j0 + 4 * g + q) * 256 + ct * 16 + r] = b16(O[ct][q] * inv[q]);
        }
    }
}

// ---------------- final conv: out[b][o][n] = sum_c Wv[o][c]*fghT[b*N+n][c] + bv[o] (f32) ----------------
__global__ __launch_bounds__(256) void k_conv_out(
    const u16* __restrict__ WVB, const u16* __restrict__ OT,
    const float* __restrict__ bv, float* __restrict__ out) {
    int bidn = blockIdx.x & 255, bido = blockIdx.x >> 8;
    int w = threadIdx.x >> 6, lane = threadIdx.x & 63, r = lane & 15, g = lane >> 4;
    int o0 = bido * 64 + w * 16, n0 = bidn * 64;
    f32x4 acc[4];
#pragma unroll
    for (int i = 0; i < 4; ++i) acc[i] = {0.f, 0.f, 0.f, 0.f};
    const u16* arow = WVB + (size_t)(o0 + r) * 256;
#pragma unroll
    for (int ks = 0; ks < 8; ++ks) {
        int k0 = ks * 32 + 8 * g;
        short8 a = ld8(arow + k0);
#pragma unroll
        for (int ntl = 0; ntl < 4; ++ntl) {
            short8 bb = ld8(OT + (size_t)(n0 + ntl * 16 + r) * 256 + k0);
            acc[ntl] = MFMA(a, bb, acc[ntl]);
        }
    }
#pragma unroll
    for (int ntl = 0; ntl < 4; ++ntl) {
#pragma unroll
        for (int q = 0; q < 4; ++q) {
            int o = o0 + 4 * g + q;
            int nf = n0 + ntl * 16 + r;
            int bb = nf >> 12, n = nf & 4095;
            out[((size_t)(bb * 256 + o)) * 4096 + n] = acc[ntl][q] + bv[o];
        }
    }
}

extern "C" void kernel_launch(void* const* d_in, const int* in_sizes, int n_in,
                              void* d_out, int out_size, void* d_ws, size_t ws_size,
                              hipStream_t stream) {
    const float* x  = (const float*)d_in[0];
    const float* Wf = (const float*)d_in[1];
    const float* bf = (const float*)d_in[2];
    const float* Wg = (const float*)d_in[3];
    const float* bg = (const float*)d_in[4];
    const float* Wh = (const float*)d_in[5];
    const float* bh = (const float*)d_in[6];
    const float* Wv = (const float*)d_in[7];
    const float* bv = (const float*)d_in[8];
    float* out = (float*)d_out;
    char* ws = (char*)d_ws;

    u16* WFH = (u16*)(ws + OFF_WFH);
    u16* WFL = (u16*)(ws + OFF_WFL);
    u16* WGH = (u16*)(ws + OFF_WGH);
    u16* WGL = (u16*)(ws + OFF_WGL);
    u16* WHB = (u16*)(ws + OFF_WHB);
    u16* WVB = (u16*)(ws + OFF_WVB);
    u16* XTH = (u16*)(ws + OFF_XTH);
    u16* XTL = (u16*)(ws + OFF_XTL);
    u16* FH  = (u16*)(ws + OFF_FH);
    u16* FL  = (u16*)(ws + OFF_FL);
    u16* GH  = (u16*)(ws + OFF_GH);
    u16* GL  = (u16*)(ws + OFF_GL);
    u16* HB  = (u16*)(ws + OFF_HB);
    u16* OT  = (u16*)(ws + OFF_OT);

    k_prep_w<<<256, 256, 0, stream>>>(Wf, Wg, Wh, Wv, WFH, WFL, WGH, WGL, WHB, WVB);
    k_prep_x<<<1024, 256, 0, stream>>>(x, XTH, XTL);
    k_conv_fg<<<1024, 256, 0, stream>>>(XTH, XTL, WFH, WFL, WGH, WGL, bf, bg, FH, FL, GH, GL);
    k_conv_h<<<1024, 256, 0, stream>>>(WHB, XTH, bh, HB);
    k_attn<<<1024, 64, 0, stream>>>(FH, FL, GH, GL, HB, OT);
    k_conv_out<<<1024, 256, 0, stream>>>(WVB, OT, bv, out);
}

// Round 2
// 688.613 us; speedup vs baseline: 1.1560x; 1.1560x over previous
//
#include <hip/hip_runtime.h>
#include <hip/hip_bf16.h>

// SAGAN attention block: B=4, C=256, N=64*64=4096.
// Round 2: fp16 attention path (1-pass QK/PV), flash-decoding key-split x4 + merge,
// XCD-aware block swizzle. Convs for f,g remain 3-pass split-bf16 for S accuracy.

typedef short short8 __attribute__((ext_vector_type(8)));
typedef float f32x4 __attribute__((ext_vector_type(4)));
typedef _Float16 f16x8 __attribute__((ext_vector_type(8)));
typedef unsigned short u16;

#define DEV static __device__ __forceinline__
#define MFMA(a, b, c)   __builtin_amdgcn_mfma_f32_16x16x32_bf16(a, b, c, 0, 0, 0)
#define MFMA16(a, b, c) __builtin_amdgcn_mfma_f32_16x16x32_f16(a, b, c, 0, 0, 0)

DEV u16 b16(float x) {
    __hip_bfloat16 h = __float2bfloat16(x);
    return *reinterpret_cast<u16*>(&h);
}
DEV float f16f(u16 u) {
    union { unsigned int ui; float f; } c;
    c.ui = ((unsigned int)u) << 16;
    return c.f;
}
DEV u16 h16(float x) {
    union { _Float16 h; u16 u; } c;
    c.h = (_Float16)x;
    return c.u;
}
DEV short8 ld8(const u16* p) { return *reinterpret_cast<const short8*>(p); }
DEV f16x8 ldh8(const u16* p) { return *reinterpret_cast<const f16x8*>(p); }

// ---- workspace byte offsets ----
constexpr size_t OFF_WFH = 0;         // 128K bf16 hi
constexpr size_t OFF_WFL = 131072;    // 128K bf16 lo
constexpr size_t OFF_WGH = 262144;
constexpr size_t OFF_WGL = 393216;
constexpr size_t OFF_WHB = 524288;    // 128K bf16
constexpr size_t OFF_WVB = 655360;    // 128K fp16
constexpr size_t OFF_ML  = 786432;    // 512K f32 pairs (4 splits x 16384 x {m,l})
constexpr size_t OFF_F   = 1310720;   // 8M fp16 [m][c]
constexpr size_t OFF_G   = OFF_F + 8388608;    //  9699328
constexpr size_t OFF_H   = OFF_G + 8388608;    // 18087936  fp16 [b][c][n]
constexpr size_t OFF_XTH = OFF_H + 8388608;    // 26476544  bf16 [m][c]
constexpr size_t OFF_XTL = OFF_XTH + 8388608;  // 34865152
constexpr size_t OFF_OP  = OFF_XTH;            // 32M fp16, aliases dead XtH/XtL
constexpr size_t OFF_OT  = OFF_F;              // 8M fp16, aliases dead F
// high-water mark = OFF_OP + 33554432 = 60,030,976 bytes

// ---------------- weight prep ----------------
__global__ __launch_bounds__(256) void k_prep_w(
    const float* __restrict__ Wf, const float* __restrict__ Wg,
    const float* __restrict__ Wh, const float* __restrict__ Wv,
    u16* WFH, u16* WFL, u16* WGH, u16* WGL, u16* WHB, u16* WVB) {
    int i = blockIdx.x * 256 + threadIdx.x;  // 65536 threads exactly
    float fv = Wf[i];
    u16 fh = b16(fv);
    WFH[i] = fh;
    WFL[i] = b16(fv - f16f(fh));
    float gv = Wg[i];
    u16 gh = b16(gv);
    WGH[i] = gh;
    WGL[i] = b16(gv - f16f(gh));
    WHB[i] = b16(Wh[i]);
    WVB[i] = h16(Wv[i]);
}

// ---------------- x transpose + split: x[b][c][n] f32 -> Xt[b][n][c] bf16 hi/lo ----------------
__global__ __launch_bounds__(256) void k_prep_x(const float* __restrict__ x, u16* XtH, u16* XtL) {
    __shared__ float lds[64][65];
    int bid = blockIdx.x;                 // 1024 blocks: b(4) x ctile(4) x ntile(64)
    int b = bid >> 8, rem = bid & 255, ct = rem >> 6, nt = rem & 63;
    int tid = threadIdx.x;
    int tx = tid & 63, ty = tid >> 6;
    const float* src = x + ((size_t)(b * 256 + ct * 64)) * 4096 + nt * 64;
#pragma unroll
    for (int k = 0; k < 16; ++k) {
        int cl = ty * 16 + k;
        lds[cl][tx] = src[(size_t)cl * 4096 + tx];
    }
    __syncthreads();
    int nl = tid >> 2, cg = tid & 3;
    short8 h0, h1, l0, l1;
#pragma unroll
    for (int j = 0; j < 8; ++j) {
        float v = lds[cg * 16 + j][nl];
        u16 hb = b16(v);
        h0[j] = (short)hb;
        l0[j] = (short)b16(v - f16f(hb));
    }
#pragma unroll
    for (int j = 8; j < 16; ++j) {
        float v = lds[cg * 16 + j][nl];
        u16 hb = b16(v);
        h1[j - 8] = (short)hb;
        l1[j - 8] = (short)b16(v - f16f(hb));
    }
    size_t dst = ((size_t)(b * 4096 + nt * 64 + nl)) * 256 + ct * 64 + cg * 16;
    *reinterpret_cast<short8*>(XtH + dst) = h0;
    *reinterpret_cast<short8*>(XtH + dst + 8) = h1;
    *reinterpret_cast<short8*>(XtL + dst) = l0;
    *reinterpret_cast<short8*>(XtL + dst + 8) = l1;
}

// ---------------- conv f,g: 3-pass split-bf16 MFMA, fp16 out ----------------
__global__ __launch_bounds__(256) void k_conv_fg(
    const u16* __restrict__ XtH, const u16* __restrict__ XtL,
    const u16* __restrict__ WFH, const u16* __restrict__ WFL,
    const u16* __restrict__ WGH, const u16* __restrict__ WGL,
    const float* __restrict__ bf, const float* __restrict__ bg,
    u16* F, u16* G) {
    int bidm = blockIdx.x & 255, bido = blockIdx.x >> 8;
    int w = threadIdx.x >> 6, lane = threadIdx.x & 63, r = lane & 15, g = lane >> 4;
    int m0 = bidm * 64 + w * 16, o0 = bido * 64;
    f32x4 fa[4], ga[4];
#pragma unroll
    for (int i = 0; i < 4; ++i) { fa[i] = {0.f, 0.f, 0.f, 0.f}; ga[i] = {0.f, 0.f, 0.f, 0.f}; }
    const u16* arh = XtH + (size_t)(m0 + r) * 256;
    const u16* arl = XtL + (size_t)(m0 + r) * 256;
#pragma unroll
    for (int ks = 0; ks < 8; ++ks) {
        int k0 = ks * 32 + 8 * g;
        short8 ah = ld8(arh + k0);
        short8 al = ld8(arl + k0);
#pragma unroll
        for (int ot = 0; ot < 4; ++ot) {
            size_t wrow = (size_t)(o0 + ot * 16 + r) * 256 + k0;
            short8 wfh = ld8(WFH + wrow), wfl = ld8(WFL + wrow);
            short8 wgh = ld8(WGH + wrow), wgl = ld8(WGL + wrow);
            fa[ot] = MFMA(ah, wfh, fa[ot]);
            fa[ot] = MFMA(ah, wfl, fa[ot]);
            fa[ot] = MFMA(al, wfh, fa[ot]);
            ga[ot] = MFMA(ah, wgh, ga[ot]);
            ga[ot] = MFMA(ah, wgl, ga[ot]);
            ga[ot] = MFMA(al, wgh, ga[ot]);
        }
    }
#pragma unroll
    for (int ot = 0; ot < 4; ++ot) {
#pragma unroll
        for (int q = 0; q < 4; ++q) {
            int row = m0 + 4 * g + q;
            int col = o0 + ot * 16 + r;
            size_t idx = (size_t)row * 256 + col;
            F[idx] = h16(fa[ot][q] + bf[col]);
            G[idx] = h16(ga[ot][q] + bg[col]);
        }
    }
}

// ---------------- conv h: bf16 MFMA, fp16 out, layout [b][c][n] ----------------
__global__ __launch_bounds__(256) void k_conv_h(
    const u16* __restrict__ WHB, const u16* __restrict__ XtH,
    const float* __restrict__ bh, u16* Hb) {
    int bidn = blockIdx.x & 255, bido = blockIdx.x >> 8;
    int w = threadIdx.x >> 6, lane = threadIdx.x & 63, r = lane & 15, g = lane >> 4;
    int o0 = bido * 64 + w * 16, n0 = bidn * 64;
    f32x4 acc[4];
#pragma unroll
    for (int i = 0; i < 4; ++i) acc[i] = {0.f, 0.f, 0.f, 0.f};
    const u16* arow = WHB + (size_t)(o0 + r) * 256;
#pragma unroll
    for (int ks = 0; ks < 8; ++ks) {
        int k0 = ks * 32 + 8 * g;
        short8 a = ld8(arow + k0);
#pragma unroll
        for (int ntl = 0; ntl < 4; ++ntl) {
            short8 bb = ld8(XtH + (size_t)(n0 + ntl * 16 + r) * 256 + k0);
            acc[ntl] = MFMA(a, bb, acc[ntl]);
        }
    }
#pragma unroll
    for (int ntl = 0; ntl < 4; ++ntl) {
#pragma unroll
        for (int q = 0; q < 4; ++q) {
            int o = o0 + 4 * g + q;
            int nf = n0 + ntl * 16 + r;
            int bb = nf >> 12, n = nf & 4095;
            Hb[((size_t)(bb * 256 + o)) * 4096 + n] = h16(acc[ntl][q] + bh[o]);
        }
    }
}

// ---------------- flash attention, key-split x4, fp16, partial outputs ----------------
DEV float rmax16(float v) {
    v = fmaxf(v, __shfl_xor(v, 1));
    v = fmaxf(v, __shfl_xor(v, 2));
    v = fmaxf(v, __shfl_xor(v, 4));
    v = fmaxf(v, __shfl_xor(v, 8));
    return v;
}
DEV float rsum16(float v) {
    v += __shfl_xor(v, 1);
    v += __shfl_xor(v, 2);
    v += __shfl_xor(v, 4);
    v += __shfl_xor(v, 8);
    return v;
}

__global__ __launch_bounds__(64, 2) void k_attn(
    const u16* __restrict__ F, const u16* __restrict__ G,
    const u16* __restrict__ Hb, u16* __restrict__ OP, float* __restrict__ ML) {
    // XCD-aware decode: bid%8 -> XCD (heuristic round-robin dispatch); xcd = b*2+p
    int bid = blockIdx.x;            // 4096 = 4b x 256jt x 4ks
    int xcd = bid & 7, idx = bid >> 3;
    int b = xcd >> 1, p = xcd & 1;
    int ks = idx & 3;
    int jt = ((idx >> 2) << 1) | p;  // 0..255
    int lane = threadIdx.x, r = lane & 15, g = lane >> 4;
    int j0 = jt * 16;
    const float L2E = 1.4426950408889634f;

    // Q (g-projection) resident in registers: A-frag rows j=r
    f16x8 Qf[8];
    {
        const u16* q = G + (size_t)(b * 4096 + j0 + r) * 256;
#pragma unroll
        for (int k = 0; k < 8; ++k) Qf[k] = ldh8(q + k * 32 + 8 * g);
    }
    f32x4 O[16];
#pragma unroll
    for (int i = 0; i < 16; ++i) O[i] = {0.f, 0.f, 0.f, 0.f};
    float m[4], l[4];
#pragma unroll
    for (int q = 0; q < 4; ++q) { m[q] = -1e30f; l[q] = 0.f; }

    __shared__ u16 P[16][72];  // padded

    int i0beg = ks * 1024;
    for (int i0 = i0beg; i0 < i0beg + 1024; i0 += 64) {
        f32x4 s[4];
#pragma unroll
        for (int it = 0; it < 4; ++it) s[it] = {0.f, 0.f, 0.f, 0.f};
#pragma unroll
        for (int it = 0; it < 4; ++it) {
            const u16* kr = F + (size_t)(b * 4096 + i0 + it * 16 + r) * 256;
#pragma unroll
            for (int k = 0; k < 8; ++k) s[it] = MFMA16(Qf[k], ldh8(kr + k * 32 + 8 * g), s[it]);
        }
        // online softmax; row j = 4g+q lives in 16 lanes of group g, cols = r
        float corr[4];
#pragma unroll
        for (int q = 0; q < 4; ++q) {
            float v = fmaxf(fmaxf(s[0][q], s[1][q]), fmaxf(s[2][q], s[3][q]));
            v = rmax16(v);
            float mn = fmaxf(m[q], v);
            corr[q] = exp2f((m[q] - mn) * L2E);
            float rs = 0.f;
#pragma unroll
            for (int it = 0; it < 4; ++it) {
                float pv = exp2f((s[it][q] - mn) * L2E);
                s[it][q] = pv;
                rs += pv;
            }
            rs = rsum16(rs);
            l[q] = l[q] * corr[q] + rs;
            m[q] = mn;
        }
#pragma unroll
        for (int ct = 0; ct < 16; ++ct) {
            O[ct][0] *= corr[0];
            O[ct][1] *= corr[1];
            O[ct][2] *= corr[2];
            O[ct][3] *= corr[3];
        }
        // P -> LDS (fp16), re-read as A-frags
#pragma unroll
        for (int it = 0; it < 4; ++it) {
#pragma unroll
            for (int q = 0; q < 4; ++q) P[4 * g + q][it * 16 + r] = h16(s[it][q]);
        }
        __syncthreads();
        f16x8 pa0 = *reinterpret_cast<const f16x8*>(&P[r][8 * g]);
        f16x8 pa1 = *reinterpret_cast<const f16x8*>(&P[r][32 + 8 * g]);
#pragma unroll
        for (int ct = 0; ct < 16; ++ct) {
            const u16* vrow = Hb + (size_t)(b * 256 + ct * 16 + r) * 4096 + i0 + 8 * g;
            f16x8 v0 = ldh8(vrow);
            f16x8 v1 = ldh8(vrow + 32);
            O[ct] = MFMA16(pa0, v0, O[ct]);
            O[ct] = MFMA16(pa1, v1, O[ct]);
        }
        __syncthreads();
    }
    // store unnormalized partial O (fp16) + (m,l)
#pragma unroll
    for (int ct = 0; ct < 16; ++ct) {
#pragma unroll
        for (int q = 0; q < 4; ++q) {
            OP[((size_t)ks * 16384 + b * 4096 + j0 + 4 * g + q) * 256 + ct * 16 + r] = h16(O[ct][q]);
        }
    }
    if (r == 0) {
#pragma unroll
        for (int q = 0; q < 4; ++q) {
            size_t mi = ((size_t)ks * 16384 + b * 4096 + j0 + 4 * g + q) * 2;
            ML[mi] = m[q];
            ML[mi + 1] = l[q];
        }
    }
}

// ---------------- merge key-splits -> OT fp16 [m][c] ----------------
__global__ __launch_bounds__(256) void k_merge(
    const u16* __restrict__ OP, const float* __restrict__ ML, u16* __restrict__ OT) {
    int t = blockIdx.x * 256 + threadIdx.x;  // 524288 threads
    int m = t >> 5;
    int c0 = (t & 31) * 8;
    const float L2E = 1.4426950408889634f;
    float mm[4], ll[4];
    float M = -1e30f;
#pragma unroll
    for (int ks = 0; ks < 4; ++ks) {
        size_t mi = ((size_t)ks * 16384 + m) * 2;
        mm[ks] = ML[mi];
        ll[ks] = ML[mi + 1];
        M = fmaxf(M, mm[ks]);
    }
    float w[4], L = 0.f;
#pragma unroll
    for (int ks = 0; ks < 4; ++ks) {
        w[ks] = exp2f((mm[ks] - M) * L2E);
        L += w[ks] * ll[ks];
    }
    float inv = 1.f / L;
    float acc[8];
#pragma unroll
    for (int j = 0; j < 8; ++j) acc[j] = 0.f;
#pragma unroll
    for (int ks = 0; ks < 4; ++ks) {
        f16x8 v = ldh8(OP + ((size_t)ks * 16384 + m) * 256 + c0);
#pragma unroll
        for (int j = 0; j < 8; ++j) acc[j] += w[ks] * (float)v[j];
    }
    short8 outp;
#pragma unroll
    for (int j = 0; j < 8; ++j) outp[j] = (short)h16(acc[j] * inv);
    *reinterpret_cast<short8*>(OT + (size_t)m * 256 + c0) = outp;
}

// ---------------- final conv: fp16 MFMA, f32 out ----------------
__global__ __launch_bounds__(256) void k_conv_out(
    const u16* __restrict__ WVB, const u16* __restrict__ OT,
    const float* __restrict__ bv, float* __restrict__ out) {
    int bidn = blockIdx.x & 255, bido = blockIdx.x >> 8;
    int w = threadIdx.x >> 6, lane = threadIdx.x & 63, r = lane & 15, g = lane >> 4;
    int o0 = bido * 64 + w * 16, n0 = bidn * 64;
    f32x4 acc[4];
#pragma unroll
    for (int i = 0; i < 4; ++i) acc[i] = {0.f, 0.f, 0.f, 0.f};
    const u16* arow = WVB + (size_t)(o0 + r) * 256;
#pragma unroll
    for (int ks = 0; ks < 8; ++ks) {
        int k0 = ks * 32 + 8 * g;
        f16x8 a = ldh8(arow + k0);
#pragma unroll
        for (int ntl = 0; ntl < 4; ++ntl) {
            f16x8 bb = ldh8(OT + (size_t)(n0 + ntl * 16 + r) * 256 + k0);
            acc[ntl] = MFMA16(a, bb, acc[ntl]);
        }
    }
#pragma unroll
    for (int ntl = 0; ntl < 4; ++ntl) {
#pragma unroll
        for (int q = 0; q < 4; ++q) {
            int o = o0 + 4 * g + q;
            int nf = n0 + ntl * 16 + r;
            int bb = nf >> 12, n = nf & 4095;
            out[((size_t)(bb * 256 + o)) * 4096 + n] = acc[ntl][q] + bv[o];
        }
    }
}

extern "C" void kernel_launch(void* const* d_in, const int* in_sizes, int n_in,
                              void* d_out, int out_size, void* d_ws, size_t ws_size,
                              hipStream_t stream) {
    const float* x  = (const float*)d_in[0];
    const float* Wf = (const float*)d_in[1];
    const float* bf = (const float*)d_in[2];
    const float* Wg = (const float*)d_in[3];
    const float* bg = (const float*)d_in[4];
    const float* Wh = (const float*)d_in[5];
    const float* bh = (const float*)d_in[6];
    const float* Wv = (const float*)d_in[7];
    const float* bv = (const float*)d_in[8];
    float* out = (float*)d_out;
    char* ws = (char*)d_ws;

    u16* WFH = (u16*)(ws + OFF_WFH);
    u16* WFL = (u16*)(ws + OFF_WFL);
    u16* WGH = (u16*)(ws + OFF_WGH);
    u16* WGL = (u16*)(ws + OFF_WGL);
    u16* WHB = (u16*)(ws + OFF_WHB);
    u16* WVB = (u16*)(ws + OFF_WVB);
    float* ML = (float*)(ws + OFF_ML);
    u16* F   = (u16*)(ws + OFF_F);
    u16* G   = (u16*)(ws + OFF_G);
    u16* H   = (u16*)(ws + OFF_H);
    u16* XTH = (u16*)(ws + OFF_XTH);
    u16* XTL = (u16*)(ws + OFF_XTL);
    u16* OP  = (u16*)(ws + OFF_OP);   // aliases XtH/XtL (dead after convs)
    u16* OT  = (u16*)(ws + OFF_OT);   // aliases F (dead after attn)

    k_prep_w<<<256, 256, 0, stream>>>(Wf, Wg, Wh, Wv, WFH, WFL, WGH, WGL, WHB, WVB);
    k_prep_x<<<1024, 256, 0, stream>>>(x, XTH, XTL);
    k_conv_fg<<<1024, 256, 0, stream>>>(XTH, XTL, WFH, WFL, WGH, WGL, bf, bg, F, G);
    k_conv_h<<<1024, 256, 0, stream>>>(WHB, XTH, bh, H);
    k_attn<<<4096, 64, 0, stream>>>(F, G, H, OP, ML);
    k_merge<<<2048, 256, 0, stream>>>(OP, ML, OT);
    k_conv_out<<<1024, 256, 0, stream>>>(WVB, OT, bv, out);
}

// Round 3
// 254.871 us; speedup vs baseline: 3.1234x; 2.7018x over previous
//
#include <hip/hip_runtime.h>
#include <hip/hip_bf16.h>

// SAGAN attention block: B=4, C=256, H=W=64 (N=4096).
// Round 3: k_attn rebuilt as 4-wave blocks with LDS-staged K/V via
// global_load_lds (width 16), XOR-swizzled tiles (T2, both-sides swizzle via
// pre-swizzled global source), key-split x2 + merge, XCD-aware placement.
// Conv path unchanged (3-pass split-bf16 for f,g accuracy; fp16 attn path).

typedef short short8 __attribute__((ext_vector_type(8)));
typedef float f32x4 __attribute__((ext_vector_type(4)));
typedef _Float16 f16x8 __attribute__((ext_vector_type(8)));
typedef unsigned short u16;

#define DEV static __device__ __forceinline__
#define MFMA(a, b, c)   __builtin_amdgcn_mfma_f32_16x16x32_bf16(a, b, c, 0, 0, 0)
#define MFMA16(a, b, c) __builtin_amdgcn_mfma_f32_16x16x32_f16(a, b, c, 0, 0, 0)

DEV u16 b16(float x) {
    __hip_bfloat16 h = __float2bfloat16(x);
    return *reinterpret_cast<u16*>(&h);
}
DEV float f16f(u16 u) {
    union { unsigned int ui; float f; } c;
    c.ui = ((unsigned int)u) << 16;
    return c.f;
}
DEV u16 h16(float x) {
    union { _Float16 h; u16 u; } c;
    c.h = (_Float16)x;
    return c.u;
}
DEV short8 ld8(const u16* p) { return *reinterpret_cast<const short8*>(p); }
DEV f16x8 ldh8(const u16* p) { return *reinterpret_cast<const f16x8*>(p); }

// async global->LDS, 16B per lane; dst is wave-uniform base, HW adds lane*16
DEV void gload16(const void* g, void* l) {
    __builtin_amdgcn_global_load_lds(
        (const __attribute__((address_space(1))) unsigned int*)g,
        (__attribute__((address_space(3))) unsigned int*)l, 16, 0, 0);
}

// ---- workspace byte offsets ----
constexpr size_t OFF_WFH = 0;         // 128K bf16 hi
constexpr size_t OFF_WFL = 131072;
constexpr size_t OFF_WGH = 262144;
constexpr size_t OFF_WGL = 393216;
constexpr size_t OFF_WHB = 524288;    // 128K bf16
constexpr size_t OFF_WVB = 655360;    // 128K fp16
constexpr size_t OFF_ML  = 786432;    // 256K f32 pairs (2 splits x 16384 x {m,l})
constexpr size_t OFF_F   = 1310720;   // 8M fp16 [m][c]
constexpr size_t OFF_G   = OFF_F + 8388608;
constexpr size_t OFF_H   = OFF_G + 8388608;    // fp16 [b][c][n]
constexpr size_t OFF_XTH = OFF_H + 8388608;    // bf16 [m][c]
constexpr size_t OFF_XTL = OFF_XTH + 8388608;
constexpr size_t OFF_OP  = OFF_XTH;            // 16M fp16 (2 splits), aliases dead Xt
constexpr size_t OFF_OT  = OFF_F;              // 8M fp16, aliases dead F
// high-water mark < 60 MB

// ---------------- weight prep ----------------
__global__ __launch_bounds__(256) void k_prep_w(
    const float* __restrict__ Wf, const float* __restrict__ Wg,
    const float* __restrict__ Wh, const float* __restrict__ Wv,
    u16* WFH, u16* WFL, u16* WGH, u16* WGL, u16* WHB, u16* WVB) {
    int i = blockIdx.x * 256 + threadIdx.x;
    float fv = Wf[i];
    u16 fh = b16(fv);
    WFH[i] = fh;
    WFL[i] = b16(fv - f16f(fh));
    float gv = Wg[i];
    u16 gh = b16(gv);
    WGH[i] = gh;
    WGL[i] = b16(gv - f16f(gh));
    WHB[i] = b16(Wh[i]);
    WVB[i] = h16(Wv[i]);
}

// ---------------- x transpose + split ----------------
__global__ __launch_bounds__(256) void k_prep_x(const float* __restrict__ x, u16* XtH, u16* XtL) {
    __shared__ float lds[64][65];
    int bid = blockIdx.x;
    int b = bid >> 8, rem = bid & 255, ct = rem >> 6, nt = rem & 63;
    int tid = threadIdx.x;
    int tx = tid & 63, ty = tid >> 6;
    const float* src = x + ((size_t)(b * 256 + ct * 64)) * 4096 + nt * 64;
#pragma unroll
    for (int k = 0; k < 16; ++k) {
        int cl = ty * 16 + k;
        lds[cl][tx] = src[(size_t)cl * 4096 + tx];
    }
    __syncthreads();
    int nl = tid >> 2, cg = tid & 3;
    short8 h0, h1, l0, l1;
#pragma unroll
    for (int j = 0; j < 8; ++j) {
        float v = lds[cg * 16 + j][nl];
        u16 hb = b16(v);
        h0[j] = (short)hb;
        l0[j] = (short)b16(v - f16f(hb));
    }
#pragma unroll
    for (int j = 8; j < 16; ++j) {
        float v = lds[cg * 16 + j][nl];
        u16 hb = b16(v);
        h1[j - 8] = (short)hb;
        l1[j - 8] = (short)b16(v - f16f(hb));
    }
    size_t dst = ((size_t)(b * 4096 + nt * 64 + nl)) * 256 + ct * 64 + cg * 16;
    *reinterpret_cast<short8*>(XtH + dst) = h0;
    *reinterpret_cast<short8*>(XtH + dst + 8) = h1;
    *reinterpret_cast<short8*>(XtL + dst) = l0;
    *reinterpret_cast<short8*>(XtL + dst + 8) = l1;
}

// ---------------- conv f,g: 3-pass split-bf16 MFMA, fp16 out ----------------
__global__ __launch_bounds__(256) void k_conv_fg(
    const u16* __restrict__ XtH, const u16* __restrict__ XtL,
    const u16* __restrict__ WFH, const u16* __restrict__ WFL,
    const u16* __restrict__ WGH, const u16* __restrict__ WGL,
    const float* __restrict__ bf, const float* __restrict__ bg,
    u16* F, u16* G) {
    int bidm = blockIdx.x & 255, bido = blockIdx.x >> 8;
    int w = threadIdx.x >> 6, lane = threadIdx.x & 63, r = lane & 15, g = lane >> 4;
    int m0 = bidm * 64 + w * 16, o0 = bido * 64;
    f32x4 fa[4], ga[4];
#pragma unroll
    for (int i = 0; i < 4; ++i) { fa[i] = {0.f, 0.f, 0.f, 0.f}; ga[i] = {0.f, 0.f, 0.f, 0.f}; }
    const u16* arh = XtH + (size_t)(m0 + r) * 256;
    const u16* arl = XtL + (size_t)(m0 + r) * 256;
#pragma unroll
    for (int ks = 0; ks < 8; ++ks) {
        int k0 = ks * 32 + 8 * g;
        short8 ah = ld8(arh + k0);
        short8 al = ld8(arl + k0);
#pragma unroll
        for (int ot = 0; ot < 4; ++ot) {
            size_t wrow = (size_t)(o0 + ot * 16 + r) * 256 + k0;
            short8 wfh = ld8(WFH + wrow), wfl = ld8(WFL + wrow);
            short8 wgh = ld8(WGH + wrow), wgl = ld8(WGL + wrow);
            fa[ot] = MFMA(ah, wfh, fa[ot]);
            fa[ot] = MFMA(ah, wfl, fa[ot]);
            fa[ot] = MFMA(al, wfh, fa[ot]);
            ga[ot] = MFMA(ah, wgh, ga[ot]);
            ga[ot] = MFMA(ah, wgl, ga[ot]);
            ga[ot] = MFMA(al, wgh, ga[ot]);
        }
    }
#pragma unroll
    for (int ot = 0; ot < 4; ++ot) {
#pragma unroll
        for (int q = 0; q < 4; ++q) {
            int row = m0 + 4 * g + q;
            int col = o0 + ot * 16 + r;
            size_t idx = (size_t)row * 256 + col;
            F[idx] = h16(fa[ot][q] + bf[col]);
            G[idx] = h16(ga[ot][q] + bg[col]);
        }
    }
}

// ---------------- conv h: bf16 MFMA, fp16 out, layout [b][c][n] ----------------
__global__ __launch_bounds__(256) void k_conv_h(
    const u16* __restrict__ WHB, const u16* __restrict__ XtH,
    const float* __restrict__ bh, u16* Hb) {
    int bidn = blockIdx.x & 255, bido = blockIdx.x >> 8;
    int w = threadIdx.x >> 6, lane = threadIdx.x & 63, r = lane & 15, g = lane >> 4;
    int o0 = bido * 64 + w * 16, n0 = bidn * 64;
    f32x4 acc[4];
#pragma unroll
    for (int i = 0; i < 4; ++i) acc[i] = {0.f, 0.f, 0.f, 0.f};
    const u16* arow = WHB + (size_t)(o0 + r) * 256;
#pragma unroll
    for (int ks = 0; ks < 8; ++ks) {
        int k0 = ks * 32 + 8 * g;
        short8 a = ld8(arow + k0);
#pragma unroll
        for (int ntl = 0; ntl < 4; ++ntl) {
            short8 bb = ld8(XtH + (size_t)(n0 + ntl * 16 + r) * 256 + k0);
            acc[ntl] = MFMA(a, bb, acc[ntl]);
        }
    }
#pragma unroll
    for (int ntl = 0; ntl < 4; ++ntl) {
#pragma unroll
        for (int q = 0; q < 4; ++q) {
            int o = o0 + 4 * g + q;
            int nf = n0 + ntl * 16 + r;
            int bb = nf >> 12, n = nf & 4095;
            Hb[((size_t)(bb * 256 + o)) * 4096 + n] = h16(acc[ntl][q] + bh[o]);
        }
    }
}

// ---------------- flash attention: 4-wave blocks, LDS-staged K/V ----------------
DEV float rmax16(float v) {
    v = fmaxf(v, __shfl_xor(v, 1));
    v = fmaxf(v, __shfl_xor(v, 2));
    v = fmaxf(v, __shfl_xor(v, 4));
    v = fmaxf(v, __shfl_xor(v, 8));
    return v;
}
DEV float rsum16(float v) {
    v += __shfl_xor(v, 1);
    v += __shfl_xor(v, 2);
    v += __shfl_xor(v, 4);
    v += __shfl_xor(v, 8);
    return v;
}

__global__ __launch_bounds__(256, 2) void k_attn(
    const u16* __restrict__ F, const u16* __restrict__ G,
    const u16* __restrict__ Hb, u16* __restrict__ OP, float* __restrict__ ML) {
    // K tile [64 keys][256 c] fp16, XOR-swizzled (byte ^= (row&7)<<4). 32KB.
    // First 10KB re-used as per-wave P buffers between QK-barrier and end-barrier.
    __shared__ u16 Klds[16384];
    // V tile [256 c][64 keys] fp16, XOR-swizzled (byte ^= (c&7)<<4). 32KB.
    __shared__ u16 Vlds[16384];

    int bid = blockIdx.x;             // 512 blocks = 8 xcd * 64
    int xcd = bid & 7;
    int b = xcd >> 1, ks = xcd & 1;   // each XCD: one (batch, key-half) pair
    int jt = bid >> 3;                // 0..63
    int tid = threadIdx.x;
    int w = tid >> 6, lane = tid & 63, r = lane & 15, g = lane >> 4;
    int j0 = jt * 64 + w * 16;        // wave's 16 queries
    const float L2E = 1.4426950408889634f;

    // Q (g-projection) resident in registers: A-frag rows j=r
    f16x8 Qf[8];
    {
        const u16* q = G + (size_t)(b * 4096 + j0 + r) * 256;
#pragma unroll
        for (int k = 0; k < 8; ++k) Qf[k] = ldh8(q + k * 32 + 8 * g);
    }
    f32x4 O[16];
#pragma unroll
    for (int i = 0; i < 16; ++i) O[i] = {0.f, 0.f, 0.f, 0.f};
    float m[4], l[4];
#pragma unroll
    for (int q = 0; q < 4; ++q) { m[q] = -1e30f; l[q] = 0.f; }

    const char* Fb  = (const char*)(F + (size_t)b * 4096 * 256);   // K source (batch base)
    const char* Hbb = (const char*)(Hb + (size_t)b * 256 * 4096);  // V source (batch base)
    char* Kl = (char*)Klds;
    char* Vl = (char*)Vlds;
    u16* Pw = Klds + w * 1280;  // per-wave P[16][72] u16, byte offset w*2560

    for (int i0 = ks * 2048; i0 < ks * 2048 + 2048; i0 += 64) {
        // ---- stage K,V -> LDS (linear dest, inverse-swizzled global source) ----
#pragma unroll
        for (int t = 0; t < 8; ++t) {
            int ti = w * 8 + t;
            int d = ti * 1024 + lane * 16;      // dest byte in K tile
            int row = d >> 9, cp = d & 511;
            gload16(Fb + (((size_t)(i0 + row)) << 9) + (size_t)(cp ^ ((row & 7) << 4)),
                    Kl + ti * 1024);
        }
#pragma unroll
        for (int t = 0; t < 8; ++t) {
            int ti = w * 8 + t;
            int d = ti * 1024 + lane * 16;      // dest byte in V tile
            int c = d >> 7, kb = d & 127;
            gload16(Hbb + (((size_t)c) << 13) + (size_t)(i0 * 2) + (size_t)(kb ^ ((c & 7) << 4)),
                    Vl + ti * 1024);
        }
        __syncthreads();  // drains vmcnt: tiles ready

        // ---- QK^T: S'[j][i], B-frags from swizzled Klds ----
        f32x4 s[4];
#pragma unroll
        for (int it = 0; it < 4; ++it) s[it] = {0.f, 0.f, 0.f, 0.f};
#pragma unroll
        for (int it = 0; it < 4; ++it) {
            int row = it * 16 + r;
            const char* kr = Kl + row * 512;
            int sw = (row & 7) << 4;
#pragma unroll
            for (int k = 0; k < 8; ++k) {
                f16x8 kb = *reinterpret_cast<const f16x8*>(kr + ((k * 64 + 16 * g) ^ sw));
                s[it] = MFMA16(Qf[k], kb, s[it]);
            }
        }
        // ---- online softmax: row j=4g+q across 16 lanes of group g ----
        float corr[4];
#pragma unroll
        for (int q = 0; q < 4; ++q) {
            float v = fmaxf(fmaxf(s[0][q], s[1][q]), fmaxf(s[2][q], s[3][q]));
            v = rmax16(v);
            float mn = fmaxf(m[q], v);
            corr[q] = exp2f((m[q] - mn) * L2E);
            float rs = 0.f;
#pragma unroll
            for (int it = 0; it < 4; ++it) {
                float pv = exp2f((s[it][q] - mn) * L2E);
                s[it][q] = pv;
                rs += pv;
            }
            rs = rsum16(rs);
            l[q] = l[q] * corr[q] + rs;
            m[q] = mn;
        }
#pragma unroll
        for (int ct = 0; ct < 16; ++ct) {
            O[ct][0] *= corr[0];
            O[ct][1] *= corr[1];
            O[ct][2] *= corr[2];
            O[ct][3] *= corr[3];
        }
        __syncthreads();  // all waves done reading Klds; P may overwrite it

        // ---- P -> LDS (D-layout), re-read as A-frags (own-wave data only) ----
#pragma unroll
        for (int it = 0; it < 4; ++it) {
#pragma unroll
            for (int q = 0; q < 4; ++q) Pw[(4 * g + q) * 72 + it * 16 + r] = h16(s[it][q]);
        }
        __asm__ volatile("s_waitcnt lgkmcnt(0)" ::: "memory");
        f16x8 pa0 = *reinterpret_cast<const f16x8*>((const char*)Pw + r * 144 + 16 * g);
        f16x8 pa1 = *reinterpret_cast<const f16x8*>((const char*)Pw + r * 144 + 64 + 16 * g);

        // ---- PV: O[j][c] += P[j][i] * V[i][c], B-frags from swizzled Vlds ----
#pragma unroll
        for (int ct = 0; ct < 16; ++ct) {
            int c = ct * 16 + r;
            const char* vr = Vl + c * 128;
            int sw = (c & 7) << 4;
            f16x8 v0 = *reinterpret_cast<const f16x8*>(vr + ((16 * g) ^ sw));
            f16x8 v1 = *reinterpret_cast<const f16x8*>(vr + ((64 + 16 * g) ^ sw));
            O[ct] = MFMA16(pa0, v0, O[ct]);
            O[ct] = MFMA16(pa1, v1, O[ct]);
        }
        __syncthreads();  // all waves done with Vlds/P before next stage
    }
    // store unnormalized partial O (fp16) + (m,l)
#pragma unroll
    for (int ct = 0; ct < 16; ++ct) {
#pragma unroll
        for (int q = 0; q < 4; ++q) {
            OP[((size_t)ks * 16384 + b * 4096 + j0 + 4 * g + q) * 256 + ct * 16 + r] = h16(O[ct][q]);
        }
    }
    if (r == 0) {
#pragma unroll
        for (int q = 0; q < 4; ++q) {
            size_t mi = ((size_t)ks * 16384 + b * 4096 + j0 + 4 * g + q) * 2;
            ML[mi] = m[q];
            ML[mi + 1] = l[q];
        }
    }
}

// ---------------- merge key-splits (x2) -> OT fp16 [m][c] ----------------
__global__ __launch_bounds__(256) void k_merge(
    const u16* __restrict__ OP, const float* __restrict__ ML, u16* __restrict__ OT) {
    int t = blockIdx.x * 256 + threadIdx.x;  // 524288 threads
    int m = t >> 5;
    int c0 = (t & 31) * 8;
    const float L2E = 1.4426950408889634f;
    float m0 = ML[(size_t)m * 2], l0 = ML[(size_t)m * 2 + 1];
    float m1 = ML[((size_t)16384 + m) * 2], l1 = ML[((size_t)16384 + m) * 2 + 1];
    float M = fmaxf(m0, m1);
    float w0 = exp2f((m0 - M) * L2E), w1 = exp2f((m1 - M) * L2E);
    float inv = 1.f / (w0 * l0 + w1 * l1);
    f16x8 v0 = ldh8(OP + (size_t)m * 256 + c0);
    f16x8 v1 = ldh8(OP + ((size_t)16384 + m) * 256 + c0);
    short8 outp;
#pragma unroll
    for (int j = 0; j < 8; ++j) outp[j] = (short)h16((w0 * (float)v0[j] + w1 * (float)v1[j]) * inv);
    *reinterpret_cast<short8*>(OT + (size_t)m * 256 + c0) = outp;
}

// ---------------- final conv: fp16 MFMA, f32 out ----------------
__global__ __launch_bounds__(256) void k_conv_out(
    const u16* __restrict__ WVB, const u16* __restrict__ OT,
    const float* __restrict__ bv, float* __restrict__ out) {
    int bidn = blockIdx.x & 255, bido = blockIdx.x >> 8;
    int w = threadIdx.x >> 6, lane = threadIdx.x & 63, r = lane & 15, g = lane >> 4;
    int o0 = bido * 64 + w * 16, n0 = bidn * 64;
    f32x4 acc[4];
#pragma unroll
    for (int i = 0; i < 4; ++i) acc[i] = {0.f, 0.f, 0.f, 0.f};
    const u16* arow = WVB + (size_t)(o0 + r) * 256;
#pragma unroll
    for (int ks = 0; ks < 8; ++ks) {
        int k0 = ks * 32 + 8 * g;
        f16x8 a = ldh8(arow + k0);
#pragma unroll
        for (int ntl = 0; ntl < 4; ++ntl) {
            f16x8 bb = ldh8(OT + (size_t)(n0 + ntl * 16 + r) * 256 + k0);
            acc[ntl] = MFMA16(a, bb, acc[ntl]);
        }
    }
#pragma unroll
    for (int ntl = 0; ntl < 4; ++ntl) {
#pragma unroll
        for (int q = 0; q < 4; ++q) {
            int o = o0 + 4 * g + q;
            int nf = n0 + ntl * 16 + r;
            int bb = nf >> 12, n = nf & 4095;
            out[((size_t)(bb * 256 + o)) * 4096 + n] = acc[ntl][q] + bv[o];
        }
    }
}

extern "C" void kernel_launch(void* const* d_in, const int* in_sizes, int n_in,
                              void* d_out, int out_size, void* d_ws, size_t ws_size,
                              hipStream_t stream) {
    const float* x  = (const float*)d_in[0];
    const float* Wf = (const float*)d_in[1];
    const float* bf = (const float*)d_in[2];
    const float* Wg = (const float*)d_in[3];
    const float* bg = (const float*)d_in[4];
    const float* Wh = (const float*)d_in[5];
    const float* bh = (const float*)d_in[6];
    const float* Wv = (const float*)d_in[7];
    const float* bv = (const float*)d_in[8];
    float* out = (float*)d_out;
    char* ws = (char*)d_ws;

    u16* WFH = (u16*)(ws + OFF_WFH);
    u16* WFL = (u16*)(ws + OFF_WFL);
    u16* WGH = (u16*)(ws + OFF_WGH);
    u16* WGL = (u16*)(ws + OFF_WGL);
    u16* WHB = (u16*)(ws + OFF_WHB);
    u16* WVB = (u16*)(ws + OFF_WVB);
    float* ML = (float*)(ws + OFF_ML);
    u16* F   = (u16*)(ws + OFF_F);
    u16* G   = (u16*)(ws + OFF_G);
    u16* H   = (u16*)(ws + OFF_H);
    u16* XTH = (u16*)(ws + OFF_XTH);
    u16* XTL = (u16*)(ws + OFF_XTL);
    u16* OP  = (u16*)(ws + OFF_OP);   // aliases XtH/XtL (dead after convs)
    u16* OT  = (u16*)(ws + OFF_OT);   // aliases F (dead after attn)

    k_prep_w<<<256, 256, 0, stream>>>(Wf, Wg, Wh, Wv, WFH, WFL, WGH, WGL, WHB, WVB);
    k_prep_x<<<1024, 256, 0, stream>>>(x, XTH, XTL);
    k_conv_fg<<<1024, 256, 0, stream>>>(XTH, XTL, WFH, WFL, WGH, WGL, bf, bg, F, G);
    k_conv_h<<<1024, 256, 0, stream>>>(WHB, XTH, bh, H);
    k_attn<<<512, 256, 0, stream>>>(F, G, H, OP, ML);
    k_merge<<<2048, 256, 0, stream>>>(OP, ML, OT);
    k_conv_out<<<1024, 256, 0, stream>>>(WVB, OT, bv, out);
}